// Round 1
// baseline (452.734 us; speedup 1.0000x reference)
//
#include <hip/hip_runtime.h>
#include <hip/hip_bf16.h>

static constexpr int KDIM = 96;

__global__ void k_count(const int* __restrict__ dst, int* __restrict__ cnt, int E) {
  int e = blockIdx.x * blockDim.x + threadIdx.x;
  if (e < E) atomicAdd(&cnt[dst[e]], 1);
}

__global__ void k_dinv(const int* __restrict__ cnt, float* __restrict__ dinv, int N) {
  int i = blockIdx.x * blockDim.x + threadIdx.x;
  if (i < N) dinv[i] = rsqrtf((float)cnt[i] + 1.0f);  // +1 for self-loop
}

__global__ void k_scan1(const int* __restrict__ cnt, int* __restrict__ rowstart,
                        int* __restrict__ bsum, int N) {
  __shared__ int s[256];
  int t = threadIdx.x;
  int i = blockIdx.x * 256 + t;
  s[t] = (i < N) ? cnt[i] : 0;
  __syncthreads();
  for (int o = 1; o < 256; o <<= 1) {
    int add = (t >= o) ? s[t - o] : 0;
    __syncthreads();
    s[t] += add;
    __syncthreads();
  }
  if (i < N) rowstart[i + 1] = s[t];
  if (t == 255) bsum[blockIdx.x] = s[255];
}

__global__ void k_scan2(int* __restrict__ bsum, int NB) {
  __shared__ int s[1024];
  int t = threadIdx.x;
  s[t] = (t < NB) ? bsum[t] : 0;
  __syncthreads();
  for (int o = 1; o < 1024; o <<= 1) {
    int add = (t >= o) ? s[t - o] : 0;
    __syncthreads();
    s[t] += add;
    __syncthreads();
  }
  if (t < NB) bsum[t] = s[t];
}

__global__ void k_scan3(int* __restrict__ rowstart, const int* __restrict__ bsum, int N) {
  int i = blockIdx.x * blockDim.x + threadIdx.x;
  if (i == 0) rowstart[0] = 0;
  if (i < N && blockIdx.x > 0) rowstart[i + 1] += bsum[blockIdx.x - 1];
}

__global__ void k_scatter(const int* __restrict__ src, const int* __restrict__ dst,
                          const int* __restrict__ rowstart, int* __restrict__ cursor,
                          int* __restrict__ col, int E) {
  int e = blockIdx.x * blockDim.x + threadIdx.x;
  if (e < E) {
    int d = dst[e];
    int p = rowstart[d] + atomicAdd(&cursor[d], 1);
    col[p] = src[e];
  }
}

// out[n][j] = sum_k x[n][k] * W[k][j]   (no bias here; bias added post-aggregation)
template <int DOUT>
__global__ __launch_bounds__(256) void k_gemm(const float* __restrict__ x,
                                              const float* __restrict__ Wg,
                                              float* __restrict__ out, int N) {
  __shared__ __align__(16) float Wl[KDIM * DOUT];
  __shared__ __align__(16) float xl[64 * 97];  // stride 97 breaks bank conflicts
  int tid = threadIdx.x;
  for (int i = tid; i < KDIM * DOUT; i += 256) Wl[i] = Wg[i];
  int base = blockIdx.x * 64;
  for (int i = tid; i < 64 * KDIM; i += 256) {
    int n = i / KDIM, k = i - n * KDIM;
    int gn = base + n;
    xl[n * 97 + k] = (gn < N) ? x[(size_t)gn * KDIM + k] : 0.f;
  }
  __syncthreads();
  const int tl = tid & 7;   // j-group: float4 index
  const int tn = tid >> 3;  // 0..31 -> nodes tn and tn+32
  constexpr int M = DOUT / 32;  // float4s per thread: 96->3, 32->1
  float4 accA[M], accB[M];
#pragma unroll
  for (int m = 0; m < M; ++m) {
    accA[m] = float4{0.f, 0.f, 0.f, 0.f};
    accB[m] = float4{0.f, 0.f, 0.f, 0.f};
  }
  const float4* W4 = (const float4*)Wl;
#pragma unroll 4
  for (int k = 0; k < KDIM; ++k) {
    float xa = xl[tn * 97 + k];
    float xb = xl[(tn + 32) * 97 + k];
#pragma unroll
    for (int m = 0; m < M; ++m) {
      float4 ww = W4[k * (DOUT / 4) + tl + 8 * m];
      accA[m].x = fmaf(xa, ww.x, accA[m].x);
      accA[m].y = fmaf(xa, ww.y, accA[m].y);
      accA[m].z = fmaf(xa, ww.z, accA[m].z);
      accA[m].w = fmaf(xa, ww.w, accA[m].w);
      accB[m].x = fmaf(xb, ww.x, accB[m].x);
      accB[m].y = fmaf(xb, ww.y, accB[m].y);
      accB[m].z = fmaf(xb, ww.z, accB[m].z);
      accB[m].w = fmaf(xb, ww.w, accB[m].w);
    }
  }
  int nA = base + tn, nB = base + tn + 32;
#pragma unroll
  for (int m = 0; m < M; ++m) {
    if (nA < N) ((float4*)(out + (size_t)nA * DOUT))[tl + 8 * m] = accA[m];
    if (nB < N) ((float4*)(out + (size_t)nB * DOUT))[tl + 8 * m] = accB[m];
  }
}

// out[v] = act( dinv[v]*( sum_{u in N(v)} dinv[u]*t[u] + dinv[v]*t[v] ) + bias )
template <int D, bool RELU>
__global__ __launch_bounds__(256) void k_agg(const float* __restrict__ t,
                                             const int* __restrict__ rowstart,
                                             const int* __restrict__ col,
                                             const float* __restrict__ dinv,
                                             const float* __restrict__ bias,
                                             float* __restrict__ out, int N) {
  constexpr int L0 = (D < 64) ? D : 64;  // lanes active for feature block 0
  int wv = threadIdx.x >> 6;
  int lane = threadIdx.x & 63;
  int v = blockIdx.x * 4 + wv;
  if (v >= N) return;
  float dv = dinv[v];
  float acc0 = 0.f, acc1 = 0.f;
  {  // self-loop
    const float* tr = t + (size_t)v * D;
    if (lane < L0) acc0 = dv * tr[lane];
    if (D == 96 && lane < 32) acc1 = dv * tr[64 + lane];
  }
  int e0 = rowstart[v], e1 = rowstart[v + 1];
  for (int e = e0; e < e1; ++e) {
    int u = col[e];
    float wu = dinv[u];
    const float* tr = t + (size_t)u * D;
    if (lane < L0) acc0 += wu * tr[lane];
    if (D == 96 && lane < 32) acc1 += wu * tr[64 + lane];
  }
  if (lane < L0) {
    float r = dv * acc0 + bias[lane];
    if (RELU) r = fmaxf(r, 0.f);
    out[(size_t)v * D + lane] = r;
  }
  if (D == 96 && lane < 32) {
    float r = dv * acc1 + bias[64 + lane];
    if (RELU) r = fmaxf(r, 0.f);
    out[(size_t)v * D + 64 + lane] = r;
  }
}

extern "C" void kernel_launch(void* const* d_in, const int* in_sizes, int n_in,
                              void* d_out, int out_size, void* d_ws, size_t ws_size,
                              hipStream_t stream) {
  const float* x  = (const float*)d_in[0];
  const int*   ei = (const int*)d_in[1];
  const float* W1 = (const float*)d_in[2];
  const float* b1 = (const float*)d_in[3];
  const float* W2 = (const float*)d_in[4];
  const float* b2 = (const float*)d_in[5];
  const float* W3 = (const float*)d_in[6];
  const float* b3 = (const float*)d_in[7];
  float* out = (float*)d_out;

  const int N = in_sizes[0] / KDIM;
  const int E = in_sizes[1] / 2;
  const int* src = ei;
  const int* dst = ei + E;

  char* w = (char*)d_ws;
  size_t off = 0;
  auto alloc = [&](size_t bytes) {
    char* p = w + off;
    off = (off + bytes + 255) & ~(size_t)255;
    return p;
  };
  int*   cnt      = (int*)alloc((size_t)N * 4);
  float* dinv     = (float*)alloc((size_t)N * 4);
  int*   rowstart = (int*)alloc((size_t)(N + 1) * 4);
  int*   cursor   = (int*)alloc((size_t)N * 4);
  int*   bsum     = (int*)alloc(4096);
  int*   col      = (int*)alloc((size_t)E * 4);
  float* tbuf     = (float*)alloc((size_t)N * KDIM * 4);
  float* hbuf     = (float*)alloc((size_t)N * KDIM * 4);

  hipMemsetAsync(cnt, 0, (size_t)N * 4, stream);
  hipMemsetAsync(cursor, 0, (size_t)N * 4, stream);

  const int TB = 256;
  const int gE = (E + TB - 1) / TB;
  const int gN = (N + TB - 1) / TB;  // == number of scan blocks NB (<=1024)
  k_count<<<gE, TB, 0, stream>>>(dst, cnt, E);
  k_dinv<<<gN, TB, 0, stream>>>(cnt, dinv, N);
  k_scan1<<<gN, 256, 0, stream>>>(cnt, rowstart, bsum, N);
  k_scan2<<<1, 1024, 0, stream>>>(bsum, gN);
  k_scan3<<<gN, 256, 0, stream>>>(rowstart, bsum, N);
  k_scatter<<<gE, TB, 0, stream>>>(src, dst, rowstart, cursor, col, E);

  const int gG = (N + 63) / 64;
  const int gA = (N + 3) / 4;
  k_gemm<96><<<gG, 256, 0, stream>>>(x, W1, tbuf, N);
  k_agg<96, true><<<gA, 256, 0, stream>>>(tbuf, rowstart, col, dinv, b1, hbuf, N);
  k_gemm<96><<<gG, 256, 0, stream>>>(hbuf, W2, tbuf, N);
  k_agg<96, true><<<gA, 256, 0, stream>>>(tbuf, rowstart, col, dinv, b2, hbuf, N);
  k_gemm<32><<<gG, 256, 0, stream>>>(hbuf, W3, tbuf, N);
  k_agg<32, false><<<gA, 256, 0, stream>>>(tbuf, rowstart, col, dinv, b3, out, N);
}

// Round 2
// 306.378 us; speedup vs baseline: 1.4777x; 1.4777x over previous
//
#include <hip/hip_runtime.h>
#include <hip/hip_bf16.h>

static constexpr int KDIM = 96;

__global__ void k_count(const int* __restrict__ dst, int* __restrict__ cnt, int E) {
  int e = blockIdx.x * blockDim.x + threadIdx.x;
  if (e < E) atomicAdd(&cnt[dst[e]], 1);
}

__global__ void k_dinv(const int* __restrict__ cnt, float* __restrict__ dinv, int N) {
  int i = blockIdx.x * blockDim.x + threadIdx.x;
  if (i < N) dinv[i] = rsqrtf((float)cnt[i] + 1.0f);  // +1 for self-loop
}

__global__ void k_scan1(const int* __restrict__ cnt, int* __restrict__ rowstart,
                        int* __restrict__ bsum, int N) {
  __shared__ int s[256];
  int t = threadIdx.x;
  int i = blockIdx.x * 256 + t;
  s[t] = (i < N) ? cnt[i] : 0;
  __syncthreads();
  for (int o = 1; o < 256; o <<= 1) {
    int add = (t >= o) ? s[t - o] : 0;
    __syncthreads();
    s[t] += add;
    __syncthreads();
  }
  if (i < N) rowstart[i + 1] = s[t];
  if (t == 255) bsum[blockIdx.x] = s[255];
}

__global__ void k_scan2(int* __restrict__ bsum, int NB) {
  __shared__ int s[1024];
  int t = threadIdx.x;
  s[t] = (t < NB) ? bsum[t] : 0;
  __syncthreads();
  for (int o = 1; o < 1024; o <<= 1) {
    int add = (t >= o) ? s[t - o] : 0;
    __syncthreads();
    s[t] += add;
    __syncthreads();
  }
  if (t < NB) bsum[t] = s[t];
}

__global__ void k_scan3(int* __restrict__ rowstart, const int* __restrict__ bsum, int N) {
  int i = blockIdx.x * blockDim.x + threadIdx.x;
  if (i == 0) rowstart[0] = 0;
  if (i < N && blockIdx.x > 0) rowstart[i + 1] += bsum[blockIdx.x - 1];
}

// Packed CSR adjacency: per edge {src_node, dinv[src] bit-cast} -> one 8B load in hot loop.
__global__ void k_scatter(const int* __restrict__ src, const int* __restrict__ dst,
                          const int* __restrict__ rowstart, int* __restrict__ cursor,
                          const float* __restrict__ dinv, int2* __restrict__ ew, int E) {
  int e = blockIdx.x * blockDim.x + threadIdx.x;
  if (e < E) {
    int d = dst[e];
    int s = src[e];
    int p = rowstart[d] + atomicAdd(&cursor[d], 1);
    ew[p] = make_int2(s, __float_as_int(dinv[s]));
  }
}

// out[n][j] = sum_k x[n][k] * W[k][j]   (no bias here; bias added post-aggregation)
template <int DOUT>
__global__ __launch_bounds__(256) void k_gemm(const float* __restrict__ x,
                                              const float* __restrict__ Wg,
                                              float* __restrict__ out, int N) {
  __shared__ __align__(16) float Wl[KDIM * DOUT];
  __shared__ __align__(16) float xl[64 * 97];  // stride 97 breaks bank conflicts
  int tid = threadIdx.x;
  for (int i = tid; i < KDIM * DOUT; i += 256) Wl[i] = Wg[i];
  int base = blockIdx.x * 64;
  for (int i = tid; i < 64 * KDIM; i += 256) {
    int n = i / KDIM, k = i - n * KDIM;
    int gn = base + n;
    xl[n * 97 + k] = (gn < N) ? x[(size_t)gn * KDIM + k] : 0.f;
  }
  __syncthreads();
  const int tl = tid & 7;   // j-group: float4 index
  const int tn = tid >> 3;  // 0..31 -> nodes tn and tn+32
  constexpr int M = DOUT / 32;  // float4s per thread: 96->3, 32->1
  float4 accA[M], accB[M];
#pragma unroll
  for (int m = 0; m < M; ++m) {
    accA[m] = float4{0.f, 0.f, 0.f, 0.f};
    accB[m] = float4{0.f, 0.f, 0.f, 0.f};
  }
  const float4* W4 = (const float4*)Wl;
#pragma unroll 4
  for (int k = 0; k < KDIM; ++k) {
    float xa = xl[tn * 97 + k];
    float xb = xl[(tn + 32) * 97 + k];
#pragma unroll
    for (int m = 0; m < M; ++m) {
      float4 ww = W4[k * (DOUT / 4) + tl + 8 * m];
      accA[m].x = fmaf(xa, ww.x, accA[m].x);
      accA[m].y = fmaf(xa, ww.y, accA[m].y);
      accA[m].z = fmaf(xa, ww.z, accA[m].z);
      accA[m].w = fmaf(xa, ww.w, accA[m].w);
      accB[m].x = fmaf(xb, ww.x, accB[m].x);
      accB[m].y = fmaf(xb, ww.y, accB[m].y);
      accB[m].z = fmaf(xb, ww.z, accB[m].z);
      accB[m].w = fmaf(xb, ww.w, accB[m].w);
    }
  }
  int nA = base + tn, nB = base + tn + 32;
#pragma unroll
  for (int m = 0; m < M; ++m) {
    if (nA < N) ((float4*)(out + (size_t)nA * DOUT))[tl + 8 * m] = accA[m];
    if (nB < N) ((float4*)(out + (size_t)nB * DOUT))[tl + 8 * m] = accB[m];
  }
}

// D=96 aggregation: wave per node, lane<48 holds float2 of features.
// out[v] = act( dinv[v]*( sum_u dinv[u]*t[u] + dinv[v]*t[v] ) + bias )
template <bool RELU>
__global__ __launch_bounds__(256) void k_agg96(const float* __restrict__ t,
                                               const int* __restrict__ rowstart,
                                               const int2* __restrict__ ew,
                                               const float* __restrict__ dinv,
                                               const float* __restrict__ bias,
                                               float* __restrict__ out, int N) {
  int wv = threadIdx.x >> 6;
  int lane = threadIdx.x & 63;
  int v = blockIdx.x * 4 + wv;
  if (v >= N) return;
  const int li = (lane < 48) ? lane : 47;  // clamp: lanes 48-63 duplicate (no divergence)
  float dv = dinv[v];
  float2 acc;
  {
    const float2* tv = (const float2*)(t + (size_t)v * 96);
    float2 r = tv[li];
    acc.x = dv * r.x;
    acc.y = dv * r.y;
  }
  int e = rowstart[v];
  const int e1 = rowstart[v + 1];
  // 4x unroll: 4 independent gather chains -> 4x memory-level parallelism
  for (; e + 4 <= e1; e += 4) {
    int2 m0 = ew[e + 0], m1 = ew[e + 1], m2 = ew[e + 2], m3 = ew[e + 3];
    const float2* r0 = (const float2*)(t + (size_t)m0.x * 96);
    const float2* r1 = (const float2*)(t + (size_t)m1.x * 96);
    const float2* r2 = (const float2*)(t + (size_t)m2.x * 96);
    const float2* r3 = (const float2*)(t + (size_t)m3.x * 96);
    float2 a0 = r0[li], a1 = r1[li], a2 = r2[li], a3 = r3[li];
    float w0 = __int_as_float(m0.y), w1 = __int_as_float(m1.y);
    float w2 = __int_as_float(m2.y), w3 = __int_as_float(m3.y);
    acc.x = fmaf(w0, a0.x, acc.x); acc.y = fmaf(w0, a0.y, acc.y);
    acc.x = fmaf(w1, a1.x, acc.x); acc.y = fmaf(w1, a1.y, acc.y);
    acc.x = fmaf(w2, a2.x, acc.x); acc.y = fmaf(w2, a2.y, acc.y);
    acc.x = fmaf(w3, a3.x, acc.x); acc.y = fmaf(w3, a3.y, acc.y);
  }
  for (; e < e1; ++e) {
    int2 m = ew[e];
    const float2* r = (const float2*)(t + (size_t)m.x * 96);
    float2 a = r[li];
    float w = __int_as_float(m.y);
    acc.x = fmaf(w, a.x, acc.x);
    acc.y = fmaf(w, a.y, acc.y);
  }
  if (lane < 48) {
    float rx = fmaf(dv, acc.x, bias[2 * lane]);
    float ry = fmaf(dv, acc.y, bias[2 * lane + 1]);
    if (RELU) { rx = fmaxf(rx, 0.f); ry = fmaxf(ry, 0.f); }
    ((float2*)(out + (size_t)v * 96))[lane] = make_float2(rx, ry);
  }
}

// D=32 aggregation: half-wave (32 lanes) per node, lane = feature. No idle lanes.
__global__ __launch_bounds__(256) void k_agg32(const float* __restrict__ t,
                                               const int* __restrict__ rowstart,
                                               const int2* __restrict__ ew,
                                               const float* __restrict__ dinv,
                                               const float* __restrict__ bias,
                                               float* __restrict__ out, int N) {
  int half = threadIdx.x >> 5;
  int lane = threadIdx.x & 31;
  int v = blockIdx.x * 8 + half;
  if (v >= N) return;
  float dv = dinv[v];
  float acc = dv * t[(size_t)v * 32 + lane];
  int e = rowstart[v];
  const int e1 = rowstart[v + 1];
  for (; e + 4 <= e1; e += 4) {
    int2 m0 = ew[e + 0], m1 = ew[e + 1], m2 = ew[e + 2], m3 = ew[e + 3];
    float a0 = t[(size_t)m0.x * 32 + lane];
    float a1 = t[(size_t)m1.x * 32 + lane];
    float a2 = t[(size_t)m2.x * 32 + lane];
    float a3 = t[(size_t)m3.x * 32 + lane];
    acc = fmaf(__int_as_float(m0.y), a0, acc);
    acc = fmaf(__int_as_float(m1.y), a1, acc);
    acc = fmaf(__int_as_float(m2.y), a2, acc);
    acc = fmaf(__int_as_float(m3.y), a3, acc);
  }
  for (; e < e1; ++e) {
    int2 m = ew[e];
    acc = fmaf(__int_as_float(m.y), t[(size_t)m.x * 32 + lane], acc);
  }
  out[(size_t)v * 32 + lane] = fmaf(dv, acc, bias[lane]);
}

extern "C" void kernel_launch(void* const* d_in, const int* in_sizes, int n_in,
                              void* d_out, int out_size, void* d_ws, size_t ws_size,
                              hipStream_t stream) {
  const float* x  = (const float*)d_in[0];
  const int*   ei = (const int*)d_in[1];
  const float* W1 = (const float*)d_in[2];
  const float* b1 = (const float*)d_in[3];
  const float* W2 = (const float*)d_in[4];
  const float* b2 = (const float*)d_in[5];
  const float* W3 = (const float*)d_in[6];
  const float* b3 = (const float*)d_in[7];
  float* out = (float*)d_out;

  const int N = in_sizes[0] / KDIM;
  const int E = in_sizes[1] / 2;
  const int* src = ei;
  const int* dst = ei + E;

  char* w = (char*)d_ws;
  size_t off = 0;
  auto alloc = [&](size_t bytes) {
    char* p = w + off;
    off = (off + bytes + 255) & ~(size_t)255;
    return p;
  };
  int*   cnt      = (int*)alloc((size_t)N * 4);
  float* dinv     = (float*)alloc((size_t)N * 4);
  int*   rowstart = (int*)alloc((size_t)(N + 1) * 4);
  int*   cursor   = (int*)alloc((size_t)N * 4);
  int*   bsum     = (int*)alloc(4096);
  int2*  ew       = (int2*)alloc((size_t)E * 8);
  float* tbuf     = (float*)alloc((size_t)N * KDIM * 4);
  float* hbuf     = (float*)alloc((size_t)N * KDIM * 4);

  hipMemsetAsync(cnt, 0, (size_t)N * 4, stream);
  hipMemsetAsync(cursor, 0, (size_t)N * 4, stream);

  const int TB = 256;
  const int gE = (E + TB - 1) / TB;
  const int gN = (N + TB - 1) / TB;
  k_count<<<gE, TB, 0, stream>>>(dst, cnt, E);
  k_dinv<<<gN, TB, 0, stream>>>(cnt, dinv, N);
  k_scan1<<<gN, 256, 0, stream>>>(cnt, rowstart, bsum, N);
  k_scan2<<<1, 1024, 0, stream>>>(bsum, gN);
  k_scan3<<<gN, 256, 0, stream>>>(rowstart, bsum, N);
  k_scatter<<<gE, TB, 0, stream>>>(src, dst, rowstart, cursor, dinv, ew, E);

  const int gG = (N + 63) / 64;
  k_gemm<96><<<gG, 256, 0, stream>>>(x, W1, tbuf, N);
  k_agg96<true><<<(N + 3) / 4, 256, 0, stream>>>(tbuf, rowstart, ew, dinv, b1, hbuf, N);
  k_gemm<96><<<gG, 256, 0, stream>>>(hbuf, W2, tbuf, N);
  k_agg96<true><<<(N + 3) / 4, 256, 0, stream>>>(tbuf, rowstart, ew, dinv, b2, hbuf, N);
  k_gemm<32><<<gG, 256, 0, stream>>>(hbuf, W3, tbuf, N);
  k_agg32<<<(N + 7) / 8, 256, 0, stream>>>(tbuf, rowstart, ew, dinv, b3, out, N);
}

// Round 3
// 268.889 us; speedup vs baseline: 1.6837x; 1.1394x over previous
//
#include <hip/hip_runtime.h>
#include <hip/hip_bf16.h>

static constexpr int KDIM = 96;
static constexpr int BSH = 7;              // 128 nodes per bucket
static constexpr int BNODES = 1 << BSH;
static constexpr int MAXBK = 400;          // >= ceil(50000/128)=391

// ---- bucketed CSR build ----------------------------------------------------

// global bucket histogram (two-level: LDS then one atomic per bucket per block)
__global__ void kb_hist(const int* __restrict__ dst, int* __restrict__ gbcnt,
                        int E, int NBK) {
  __shared__ int h[MAXBK];
  for (int i = threadIdx.x; i < NBK; i += blockDim.x) h[i] = 0;
  __syncthreads();
  for (int e = blockIdx.x * blockDim.x + threadIdx.x; e < E; e += gridDim.x * blockDim.x)
    atomicAdd(&h[dst[e] >> BSH], 1);
  __syncthreads();
  for (int i = threadIdx.x; i < NBK; i += blockDim.x)
    if (h[i]) atomicAdd(&gbcnt[i], h[i]);
}

// scan buckets -> bstart[0..NBK], bcur = bstart
__global__ void kb_scanb(const int* __restrict__ gbcnt, int* __restrict__ bstart,
                         int* __restrict__ bcur, int NBK) {
  __shared__ int s[512];
  int t = threadIdx.x;
  int v = (t < NBK) ? gbcnt[t] : 0;
  s[t] = v;
  __syncthreads();
  for (int o = 1; o < 512; o <<= 1) {
    int a = (t >= o) ? s[t - o] : 0;
    __syncthreads();
    s[t] += a;
    __syncthreads();
  }
  if (t < NBK) {
    int excl = s[t] - v;
    bstart[t] = excl;
    bcur[t] = excl;
  }
  if (t == 511) bstart[NBK] = s[511];
}

// chunk-local scatter of (src,dst) pairs into bucket regions.
// Each block owns a contiguous edge chunk; reserves per-bucket space with ONE
// global atomic per (block,bucket) -> writes stream into ~NBK active lines.
__global__ __launch_bounds__(256) void kb_scatter(const int* __restrict__ src,
                                                  const int* __restrict__ dst,
                                                  int* __restrict__ bcur,
                                                  int2* __restrict__ tmp,
                                                  int E, int NBK, int chunk) {
  __shared__ int h[MAXBK];
  __shared__ int base[MAXBK];
  int lo = blockIdx.x * chunk;
  int hi = min(lo + chunk, E);
  for (int i = threadIdx.x; i < NBK; i += 256) h[i] = 0;
  __syncthreads();
  for (int e = lo + threadIdx.x; e < hi; e += 256) atomicAdd(&h[dst[e] >> BSH], 1);
  __syncthreads();
  for (int i = threadIdx.x; i < NBK; i += 256) {
    int c = h[i];
    base[i] = c ? atomicAdd(&bcur[i], c) : 0;
    h[i] = 0;
  }
  __syncthreads();
  for (int e = lo + threadIdx.x; e < hi; e += 256) {
    int d = dst[e];
    int b = d >> BSH;
    int p = base[b] + atomicAdd(&h[b], 1);
    tmp[p] = make_int2(src[e], d);
  }
}

// per-bucket degree count (LDS histogram) + dinv, coalesced writes
__global__ __launch_bounds__(256) void kb_cnt(const int2* __restrict__ tmp,
                                              const int* __restrict__ bstart,
                                              int* __restrict__ cnt,
                                              float* __restrict__ dinv, int N) {
  __shared__ int h[BNODES];
  int b = blockIdx.x;
  for (int i = threadIdx.x; i < BNODES; i += 256) h[i] = 0;
  __syncthreads();
  int lo = bstart[b], hi = bstart[b + 1];
  for (int p = lo + threadIdx.x; p < hi; p += 256)
    atomicAdd(&h[tmp[p].y & (BNODES - 1)], 1);
  __syncthreads();
  int v0 = b << BSH;
  for (int i = threadIdx.x; i < BNODES; i += 256) {
    int v = v0 + i;
    if (v < N) {
      int c = h[i];
      cnt[v] = c;
      dinv[v] = rsqrtf((float)c + 1.0f);  // +1 self-loop
    }
  }
}

// scans over PADDED counts (rows padded to multiple of 8 edges)
__global__ void k_scan1(const int* __restrict__ cnt, int* __restrict__ rowstart,
                        int* __restrict__ bsum, int N) {
  __shared__ int s[256];
  int t = threadIdx.x;
  int i = blockIdx.x * 256 + t;
  s[t] = (i < N) ? ((cnt[i] + 7) & ~7) : 0;
  __syncthreads();
  for (int o = 1; o < 256; o <<= 1) {
    int add = (t >= o) ? s[t - o] : 0;
    __syncthreads();
    s[t] += add;
    __syncthreads();
  }
  if (i < N) rowstart[i + 1] = s[t];
  if (t == 255) bsum[blockIdx.x] = s[255];
}

__global__ void k_scan2(int* __restrict__ bsum, int NB) {
  __shared__ int s[1024];
  int t = threadIdx.x;
  s[t] = (t < NB) ? bsum[t] : 0;
  __syncthreads();
  for (int o = 1; o < 1024; o <<= 1) {
    int add = (t >= o) ? s[t - o] : 0;
    __syncthreads();
    s[t] += add;
    __syncthreads();
  }
  if (t < NB) bsum[t] = s[t];
}

__global__ void k_scan3(int* __restrict__ rowstart, const int* __restrict__ bsum, int N) {
  int i = blockIdx.x * blockDim.x + threadIdx.x;
  if (i == 0) rowstart[0] = 0;
  if (i < N && blockIdx.x > 0) rowstart[i + 1] += bsum[blockIdx.x - 1];
}

// per-bucket final scatter into padded CSR: writes confined to ~16KB window.
// Pads each row to a multiple of 8 with {src=0, w=0} (contributes nothing).
__global__ __launch_bounds__(256) void kb_final(const int2* __restrict__ tmp,
                                                const int* __restrict__ bstart,
                                                const int* __restrict__ rowstart,
                                                const float* __restrict__ dinv,
                                                int2* __restrict__ ew, int N) {
  __shared__ int prow[BNODES];
  __shared__ int lcur[BNODES];
  int b = blockIdx.x;
  int v0 = b << BSH;
  for (int i = threadIdx.x; i < BNODES; i += 256) {
    int v = v0 + i;
    prow[i] = (v < N) ? rowstart[v] : 0;
    lcur[i] = 0;
  }
  __syncthreads();
  int lo = bstart[b], hi = bstart[b + 1];
  for (int p = lo + threadIdx.x; p < hi; p += 256) {
    int2 sd = tmp[p];
    int dl = sd.y & (BNODES - 1);
    int pos = prow[dl] + atomicAdd(&lcur[dl], 1);
    ew[pos] = make_int2(sd.x, __float_as_int(dinv[sd.x]));
  }
  __syncthreads();
  for (int i = threadIdx.x; i < BNODES; i += 256) {
    int v = v0 + i;
    if (v < N) {
      int c = lcur[i];
      int p = prow[i] + c;
      int end = prow[i] + ((c + 7) & ~7);
      for (; p < end; ++p) ew[p] = make_int2(0, 0);
    }
  }
}

// ---- dense transform -------------------------------------------------------

template <int DOUT>
__global__ __launch_bounds__(256) void k_gemm(const float* __restrict__ x,
                                              const float* __restrict__ Wg,
                                              float* __restrict__ out, int N) {
  __shared__ __align__(16) float Wl[KDIM * DOUT];
  __shared__ __align__(16) float xl[64 * 97];
  int tid = threadIdx.x;
  for (int i = tid; i < KDIM * DOUT; i += 256) Wl[i] = Wg[i];
  int base = blockIdx.x * 64;
  for (int i = tid; i < 64 * KDIM; i += 256) {
    int n = i / KDIM, k = i - n * KDIM;
    int gn = base + n;
    xl[n * 97 + k] = (gn < N) ? x[(size_t)gn * KDIM + k] : 0.f;
  }
  __syncthreads();
  const int tl = tid & 7;
  const int tn = tid >> 3;
  constexpr int M = DOUT / 32;
  float4 accA[M], accB[M];
#pragma unroll
  for (int m = 0; m < M; ++m) {
    accA[m] = float4{0.f, 0.f, 0.f, 0.f};
    accB[m] = float4{0.f, 0.f, 0.f, 0.f};
  }
  const float4* W4 = (const float4*)Wl;
#pragma unroll 4
  for (int k = 0; k < KDIM; ++k) {
    float xa = xl[tn * 97 + k];
    float xb = xl[(tn + 32) * 97 + k];
#pragma unroll
    for (int m = 0; m < M; ++m) {
      float4 ww = W4[k * (DOUT / 4) + tl + 8 * m];
      accA[m].x = fmaf(xa, ww.x, accA[m].x);
      accA[m].y = fmaf(xa, ww.y, accA[m].y);
      accA[m].z = fmaf(xa, ww.z, accA[m].z);
      accA[m].w = fmaf(xa, ww.w, accA[m].w);
      accB[m].x = fmaf(xb, ww.x, accB[m].x);
      accB[m].y = fmaf(xb, ww.y, accB[m].y);
      accB[m].z = fmaf(xb, ww.z, accB[m].z);
      accB[m].w = fmaf(xb, ww.w, accB[m].w);
    }
  }
  int nA = base + tn, nB = base + tn + 32;
#pragma unroll
  for (int m = 0; m < M; ++m) {
    if (nA < N) ((float4*)(out + (size_t)nA * DOUT))[tl + 8 * m] = accA[m];
    if (nB < N) ((float4*)(out + (size_t)nB * DOUT))[tl + 8 * m] = accB[m];
  }
}

// ---- aggregation (padded CSR: every row a multiple of 8 edges) -------------

template <bool RELU>
__global__ __launch_bounds__(256) void k_agg96(const float* __restrict__ t,
                                               const int* __restrict__ rowstart,
                                               const int2* __restrict__ ew,
                                               const float* __restrict__ dinv,
                                               const float* __restrict__ bias,
                                               float* __restrict__ out, int N) {
  int wv = threadIdx.x >> 6;
  int lane = threadIdx.x & 63;
  int v = blockIdx.x * 4 + wv;
  if (v >= N) return;
  const int li = (lane < 48) ? lane : 47;  // lanes 48-63 duplicate lane 47
  float dv = dinv[v];
  float2 acc;
  {
    float2 r = ((const float2*)(t + (size_t)v * 96))[li];
    acc.x = dv * r.x;
    acc.y = dv * r.y;
  }
  int e = rowstart[v];
  const int e1 = rowstart[v + 1];
  for (; e < e1; e += 8) {  // exact: rows padded to x8, 64B-aligned
    const int4* m4 = (const int4*)(ew + e);  // wave-uniform broadcast loads
    int4 q0 = m4[0], q1 = m4[1], q2 = m4[2], q3 = m4[3];
    const float2* r0 = (const float2*)(t + (size_t)q0.x * 96);
    const float2* r1 = (const float2*)(t + (size_t)q0.z * 96);
    const float2* r2 = (const float2*)(t + (size_t)q1.x * 96);
    const float2* r3 = (const float2*)(t + (size_t)q1.z * 96);
    const float2* r4 = (const float2*)(t + (size_t)q2.x * 96);
    const float2* r5 = (const float2*)(t + (size_t)q2.z * 96);
    const float2* r6 = (const float2*)(t + (size_t)q3.x * 96);
    const float2* r7 = (const float2*)(t + (size_t)q3.z * 96);
    float2 a0 = r0[li], a1 = r1[li], a2 = r2[li], a3 = r3[li];
    float2 a4 = r4[li], a5 = r5[li], a6 = r6[li], a7 = r7[li];
    float w0 = __int_as_float(q0.y), w1 = __int_as_float(q0.w);
    float w2 = __int_as_float(q1.y), w3 = __int_as_float(q1.w);
    float w4 = __int_as_float(q2.y), w5 = __int_as_float(q2.w);
    float w6 = __int_as_float(q3.y), w7 = __int_as_float(q3.w);
    acc.x = fmaf(w0, a0.x, acc.x); acc.y = fmaf(w0, a0.y, acc.y);
    acc.x = fmaf(w1, a1.x, acc.x); acc.y = fmaf(w1, a1.y, acc.y);
    acc.x = fmaf(w2, a2.x, acc.x); acc.y = fmaf(w2, a2.y, acc.y);
    acc.x = fmaf(w3, a3.x, acc.x); acc.y = fmaf(w3, a3.y, acc.y);
    acc.x = fmaf(w4, a4.x, acc.x); acc.y = fmaf(w4, a4.y, acc.y);
    acc.x = fmaf(w5, a5.x, acc.x); acc.y = fmaf(w5, a5.y, acc.y);
    acc.x = fmaf(w6, a6.x, acc.x); acc.y = fmaf(w6, a6.y, acc.y);
    acc.x = fmaf(w7, a7.x, acc.x); acc.y = fmaf(w7, a7.y, acc.y);
  }
  if (lane < 48) {
    float rx = fmaf(dv, acc.x, bias[2 * lane]);
    float ry = fmaf(dv, acc.y, bias[2 * lane + 1]);
    if (RELU) { rx = fmaxf(rx, 0.f); ry = fmaxf(ry, 0.f); }
    ((float2*)(out + (size_t)v * 96))[lane] = make_float2(rx, ry);
  }
}

__global__ __launch_bounds__(256) void k_agg32(const float* __restrict__ t,
                                               const int* __restrict__ rowstart,
                                               const int2* __restrict__ ew,
                                               const float* __restrict__ dinv,
                                               const float* __restrict__ bias,
                                               float* __restrict__ out, int N) {
  int half = threadIdx.x >> 5;
  int lane = threadIdx.x & 31;
  int v = blockIdx.x * 8 + half;
  if (v >= N) return;
  float dv = dinv[v];
  float acc = dv * t[(size_t)v * 32 + lane];
  int e = rowstart[v];
  const int e1 = rowstart[v + 1];
  for (; e < e1; e += 8) {
    const int4* m4 = (const int4*)(ew + e);
    int4 q0 = m4[0], q1 = m4[1], q2 = m4[2], q3 = m4[3];
    float a0 = t[(size_t)q0.x * 32 + lane];
    float a1 = t[(size_t)q0.z * 32 + lane];
    float a2 = t[(size_t)q1.x * 32 + lane];
    float a3 = t[(size_t)q1.z * 32 + lane];
    float a4 = t[(size_t)q2.x * 32 + lane];
    float a5 = t[(size_t)q2.z * 32 + lane];
    float a6 = t[(size_t)q3.x * 32 + lane];
    float a7 = t[(size_t)q3.z * 32 + lane];
    acc = fmaf(__int_as_float(q0.y), a0, acc);
    acc = fmaf(__int_as_float(q0.w), a1, acc);
    acc = fmaf(__int_as_float(q1.y), a2, acc);
    acc = fmaf(__int_as_float(q1.w), a3, acc);
    acc = fmaf(__int_as_float(q2.y), a4, acc);
    acc = fmaf(__int_as_float(q2.w), a5, acc);
    acc = fmaf(__int_as_float(q3.y), a6, acc);
    acc = fmaf(__int_as_float(q3.w), a7, acc);
  }
  out[(size_t)v * 32 + lane] = fmaf(dv, acc, bias[lane]);
}

// ---- launch ----------------------------------------------------------------

extern "C" void kernel_launch(void* const* d_in, const int* in_sizes, int n_in,
                              void* d_out, int out_size, void* d_ws, size_t ws_size,
                              hipStream_t stream) {
  const float* x  = (const float*)d_in[0];
  const int*   ei = (const int*)d_in[1];
  const float* W1 = (const float*)d_in[2];
  const float* b1 = (const float*)d_in[3];
  const float* W2 = (const float*)d_in[4];
  const float* b2 = (const float*)d_in[5];
  const float* W3 = (const float*)d_in[6];
  const float* b3 = (const float*)d_in[7];
  float* out = (float*)d_out;

  const int N = in_sizes[0] / KDIM;
  const int E = in_sizes[1] / 2;
  const int* src = ei;
  const int* dst = ei + E;
  const int NBK = (N + BNODES - 1) >> BSH;

  char* w = (char*)d_ws;
  size_t off = 0;
  auto alloc = [&](size_t bytes) {
    char* p = w + off;
    off = (off + bytes + 255) & ~(size_t)255;
    return p;
  };
  int*   gbcnt    = (int*)alloc((size_t)MAXBK * 4);
  int*   bstart   = (int*)alloc((size_t)(MAXBK + 1) * 4);
  int*   bcur     = (int*)alloc((size_t)MAXBK * 4);
  int*   cnt      = (int*)alloc((size_t)N * 4);
  float* dinv     = (float*)alloc((size_t)N * 4);
  int*   rowstart = (int*)alloc((size_t)(N + 1) * 4);
  int*   bsum     = (int*)alloc(4096);
  int2*  tmp      = (int2*)alloc((size_t)E * 8);
  int2*  ew       = (int2*)alloc((size_t)(E + 8 * (size_t)N) * 8);  // padded CSR
  float* tbuf     = (float*)alloc((size_t)N * KDIM * 4);
  float* hbuf     = (float*)alloc((size_t)N * KDIM * 4);

  hipMemsetAsync(gbcnt, 0, (size_t)NBK * 4, stream);

  const int gN = (N + 255) / 256;
  const int NCH = 512;
  const int chunk = (E + NCH - 1) / NCH;

  kb_hist<<<256, 256, 0, stream>>>(dst, gbcnt, E, NBK);
  kb_scanb<<<1, 512, 0, stream>>>(gbcnt, bstart, bcur, NBK);
  kb_scatter<<<NCH, 256, 0, stream>>>(src, dst, bcur, tmp, E, NBK, chunk);
  kb_cnt<<<NBK, 256, 0, stream>>>(tmp, bstart, cnt, dinv, N);
  k_scan1<<<gN, 256, 0, stream>>>(cnt, rowstart, bsum, N);
  k_scan2<<<1, 1024, 0, stream>>>(bsum, gN);
  k_scan3<<<gN, 256, 0, stream>>>(rowstart, bsum, N);
  kb_final<<<NBK, 256, 0, stream>>>(tmp, bstart, rowstart, dinv, ew, N);

  const int gG = (N + 63) / 64;
  k_gemm<96><<<gG, 256, 0, stream>>>(x, W1, tbuf, N);
  k_agg96<true><<<(N + 3) / 4, 256, 0, stream>>>(tbuf, rowstart, ew, dinv, b1, hbuf, N);
  k_gemm<96><<<gG, 256, 0, stream>>>(hbuf, W2, tbuf, N);
  k_agg96<true><<<(N + 3) / 4, 256, 0, stream>>>(tbuf, rowstart, ew, dinv, b2, hbuf, N);
  k_gemm<32><<<gG, 256, 0, stream>>>(hbuf, W3, tbuf, N);
  k_agg32<<<(N + 7) / 8, 256, 0, stream>>>(tbuf, rowstart, ew, dinv, b3, out, N);
}